// Round 8
// baseline (151.615 us; speedup 1.0000x reference)
//
#include <hip/hip_runtime.h>
#include <hip/hip_bf16.h>
#include <math.h>

typedef __attribute__((ext_vector_type(8))) short short8;
typedef __attribute__((ext_vector_type(16))) float f32x16;

#define NB 4096
#define DIM 128
#define NJ 16                  // j-splits: each block handles NB/NJ = 256 j's
#define JTILES (NB / NJ / 32)  // 8 j-tiles of 32 per block
// EXP_SCALE = (1/TAU) * log2(e) = 20 * 1.4426950408889634
#define EXP_SCALE 28.853900817779268f

__device__ inline unsigned short f2bf(float f) {
  unsigned int u = __builtin_bit_cast(unsigned int, f);
  u += 0x7FFFu + ((u >> 16) & 1u);
  return (unsigned short)(u >> 16);
}

__device__ inline float wave_sum(float v) {
#pragma unroll
  for (int off = 32; off >= 1; off >>= 1) v += __shfl_xor(v, off, 64);
  return v;
}

// Detect int64-vs-int32 links + zero the output scalar.
__global__ __launch_bounds__(64) void k_init(const int* links32, int* flag, float* out) {
  if (threadIdx.x == 0) {
    int all0 = 1;
    for (int w = 1; w < 256; w += 2) all0 &= (links32[w] == 0);
    *flag = all0;
    out[0] = 0.0f;
  }
}

// Gather + L2-normalize the 8192 referenced rows.
__global__ __launch_bounds__(256) void k_normalize(
    const float* __restrict__ emb, const int* __restrict__ links,
    const int* __restrict__ flag,
    float* __restrict__ Zi_f, float* __restrict__ Zj_f,
    unsigned short* __restrict__ Zic, unsigned short* __restrict__ Zjc) {
  int wid = threadIdx.x >> 6, lane = threadIdx.x & 63;
  int r = blockIdx.x * 4 + wid;   // 0..8191
  int side = r >> 12;
  int p = r & (NB - 1);
  int q = 2 * p + side;
  int idx = (*flag) ? links[2 * q] : links[q];
  const float* src = emb + (long long)idx * DIM;
  float x0 = src[lane], x1 = src[lane + 64];
  float ss = wave_sum(x0 * x0 + x1 * x1);
  float inv = 1.0f / fmaxf(sqrtf(ss), 1e-12f);
  x0 *= inv; x1 *= inv;
  float* Zf = side ? Zj_f : Zi_f;
  unsigned short* Zc = side ? Zjc : Zic;
  Zf[p * DIM + lane] = x0;
  Zf[p * DIM + 64 + lane] = x1;
  Zc[(((lane >> 3) + 0) * NB + p) * 8 + (lane & 7)] = f2bf(x0);
  Zc[(((lane >> 3) + 8) * NB + p) * 8 + (lane & 7)] = f2bf(x1);
}

// diag[i] = (zis_i . zjs_i) / TAU
__global__ __launch_bounds__(256) void k_diag(
    const float* __restrict__ Zi_f, const float* __restrict__ Zj_f,
    float* __restrict__ diag) {
  int wid = threadIdx.x >> 6, lane = threadIdx.x & 63;
  int i = blockIdx.x * 4 + wid;
  float a0 = Zi_f[i * DIM + lane], a1 = Zi_f[i * DIM + 64 + lane];
  float b0 = Zj_f[i * DIM + lane], b1 = Zj_f[i * DIM + 64 + lane];
  float s = wave_sum(a0 * b0 + a1 * b1);
  if (lane == 0) diag[i] = s * 20.0f;
}

// VAR=0: real kernel (bit-identical logic to R7, verified).
// VAR=1: ABLATION — identical loads + MFMA chain, epilogue (exp/skip/adds)
//        deleted; acc kept live by consuming acc[0]+acc[8] (MFMA emits all
//        16 elems in one instr, so consuming any element prevents DCE).
template <int VAR>
__global__ __launch_bounds__(256) void k_pass(
    const unsigned short* __restrict__ Zic, const unsigned short* __restrict__ Zjc,
    float* __restrict__ rpart) {
  int z = blockIdx.z;
  const unsigned short* Xc = (z <= 1) ? Zic : Zjc;
  const unsigned short* Yc = (z == 1 || z == 2) ? Zic : Zjc;
  const bool skip = (z & 1);

  __shared__ float buf[128];
  int tid = threadIdx.x;
  int wid = tid >> 6, lane = tid & 63;
  if (tid < 128) buf[tid] = 0.0f;
  __syncthreads();

  int it0 = blockIdx.x * 128 + wid * 32;  // wave's 32 loss-rows (one tile)
  int jb = blockIdx.y * (NB / NJ);        // 256 j's = 8 tiles of 32
  int lr = lane & 31;
  int hi = lane >> 5;

  // --- dual per-reg layout probe (verified R3-R7), compressed ---
  short8 pj, pc;
  unsigned short blr = f2bf((float)lr);
#pragma unroll
  for (int e = 0; e < 8; ++e) { pj[e] = (short)blr; pc[e] = (short)0x3D80; }
  f32x16 pr = {}, pn = {};
  pr = __builtin_amdgcn_mfma_f32_32x32x16_bf16(pj, pc, pr, 0, 0, 0);
  pn = __builtin_amdgcn_mfma_f32_32x32x16_bf16(pc, pj, pn, 0, 0, 0);
  unsigned int dmask = 0;
  int imv[4] = {0, 0, 0, 0};
#pragma unroll
  for (int r = 0; r < 16; ++r) {
    int jm = (int)(pr[r] + 0.5f), im = (int)(pn[r] + 0.5f);
    dmask |= (unsigned)(jm == im) << r;
    imv[r >> 2] |= im << ((r & 3) * 8);
  }

  short8 xf[8];
#pragma unroll
  for (int ks = 0; ks < 8; ++ks)
    xf[ks] = *reinterpret_cast<const short8*>(
        Xc + ((size_t)(ks * 2 + hi) * NB + (it0 + lr)) * 8);

  float rs[16];
#pragma unroll
  for (int r = 0; r < 16; ++r) rs[r] = 0.0f;

  for (int jt = 0; jt < JTILES; ++jt) {
    int j0 = jb + jt * 32;
    short8 yf[8];
#pragma unroll
    for (int ks = 0; ks < 8; ++ks)
      yf[ks] = *reinterpret_cast<const short8*>(
          Yc + ((size_t)(ks * 2 + hi) * NB + (j0 + lr)) * 8);
    f32x16 acc = {};
#pragma unroll
    for (int ks = 0; ks < 8; ++ks)
      acc = __builtin_amdgcn_mfma_f32_32x32x16_bf16(yf[ks], xf[ks], acc, 0, 0, 0);
    if constexpr (VAR == 0) {
      bool chk = skip && (j0 == it0);
#pragma unroll
      for (int r = 0; r < 16; ++r) {
        float e = exp2f(fmaf(acc[r], EXP_SCALE, -EXP_SCALE));
        if (chk && ((dmask >> r) & 1u)) e = 0.0f;
        rs[r] += e;
      }
    } else {
      // ablation: consume acc to keep MFMAs; no exp/skip/per-reg adds
      rs[0] += acc[0] + acc[8];
    }
  }
  int base = wid * 32;
#pragma unroll
  for (int r = 0; r < 16; ++r) {
    int im = (imv[r >> 2] >> ((r & 3) * 8)) & 0xFF;
    atomicAdd(&buf[base + im], rs[r]);
  }
  __syncthreads();
  if (tid < 128)
    rpart[((size_t)(z * NJ + blockIdx.y)) * NB + blockIdx.x * 128 + tid] = buf[tid];
}

__global__ __launch_bounds__(256) void k_final(
    const float* __restrict__ rpart, const float* __restrict__ diag,
    float* __restrict__ out) {
  int i = blockIdx.x * 256 + threadIdx.x;
  float sa = 0.0f, sb = 0.0f;
#pragma unroll
  for (int y = 0; y < NJ; ++y) {
    sa += rpart[(size_t)(0 * NJ + y) * NB + i] + rpart[(size_t)(1 * NJ + y) * NB + i];
    sb += rpart[(size_t)(2 * NJ + y) * NB + i] + rpart[(size_t)(3 * NJ + y) * NB + i];
  }
  float v = 0.5f * (40.0f + logf(sa) + logf(sb)) - diag[i];
  v = wave_sum(v);
  __shared__ float sred[4];
  if ((threadIdx.x & 63) == 0) sred[threadIdx.x >> 6] = v;
  __syncthreads();
  if (threadIdx.x == 0)
    atomicAdd(out, (sred[0] + sred[1] + sred[2] + sred[3]) * (1.0f / NB));
}

extern "C" void kernel_launch(void* const* d_in, const int* in_sizes, int n_in,
                              void* d_out, int out_size, void* d_ws, size_t ws_size,
                              hipStream_t stream) {
  const float* emb = (const float*)d_in[0];
  const int* links = (const int*)d_in[1];
  char* ws = (char*)d_ws;
  float* Zi_f = (float*)(ws + 0);
  float* Zj_f = (float*)(ws + 2097152);
  unsigned short* Zic = (unsigned short*)(ws + 4194304);
  unsigned short* Zjc = (unsigned short*)(ws + 5242880);
  float* rpart = (float*)(ws + 6291456);                 // 1 MB
  float* diag = (float*)(ws + 7340032);
  int* flag = (int*)(ws + 7356416);
  float* out = (float*)d_out;

  hipLaunchKernelGGL(k_init, dim3(1), dim3(64), 0, stream, links, flag, out);
  hipLaunchKernelGGL(k_normalize, dim3(2048), dim3(256), 0, stream,
                     emb, links, flag, Zi_f, Zj_f, Zic, Zjc);
  hipLaunchKernelGGL(k_diag, dim3(1024), dim3(256), 0, stream, Zi_f, Zj_f, diag);
  // ABLATION dispatch: same grid, writes rpart (garbage), fully overwritten
  // by the real pass below — deterministic, output-safe.
  hipLaunchKernelGGL((k_pass<1>), dim3(32, NJ, 4), dim3(256), 0, stream,
                     Zic, Zjc, rpart);
  // REAL pass (R7-verified logic)
  hipLaunchKernelGGL((k_pass<0>), dim3(32, NJ, 4), dim3(256), 0, stream,
                     Zic, Zjc, rpart);
  hipLaunchKernelGGL(k_final, dim3(16), dim3(256), 0, stream,
                     rpart, diag, out);
}